// Round 1
// baseline (127.651 us; speedup 1.0000x reference)
//
#include <hip/hip_runtime.h>
#include <hip/hip_bf16.h>

#define N_ROWS 8192
#define BATCH 4096
#define DIM 256

#define NB 64           // 128-row blocks along each side
#define BR 128          // rows (and cols) per pair-block side
#define CT 16           // cols per LDS tile
#define NT 8            // tiles per block (BR/CT)
#define LDSROW 528      // 512 data bytes + 16 pad
#define LDSBUF (CT * LDSROW)
#define KEXP 2.8853900817779268f   // 2*log2(e): exp(2*dot) = exp2(dot*KEXP)

typedef __attribute__((ext_vector_type(8))) short bfrag8;
typedef __attribute__((ext_vector_type(4))) float facc4;

// ---------------- Kernel A: normalize + cast to bf16 -------------------
__global__ __launch_bounds__(256) void normalize_kernel(
    const float* __restrict__ zA, const float* __restrict__ zB,
    __hip_bfloat16* __restrict__ zn) {
    int tid = threadIdx.x;
    int wave = tid >> 6, lane = tid & 63;
    int row = blockIdx.x * 4 + wave;
    const float* src = (row < BATCH) ? (zA + (size_t)row * DIM)
                                     : (zB + (size_t)(row - BATCH) * DIM);
    float4 v = ((const float4*)src)[lane];
    float ss = v.x * v.x + v.y * v.y + v.z * v.z + v.w * v.w;
    #pragma unroll
    for (int m = 32; m; m >>= 1) ss += __shfl_xor(ss, m);
    float inv = 1.0f / fmaxf(sqrtf(ss), 1e-8f);
    union { ushort4 u; __hip_bfloat16 h[4]; } o;
    o.h[0] = __float2bfloat16(v.x * inv);
    o.h[1] = __float2bfloat16(v.y * inv);
    o.h[2] = __float2bfloat16(v.z * inv);
    o.h[3] = __float2bfloat16(v.w * inv);
    ((ushort4*)zn)[(size_t)row * (DIM / 4) + lane] = o.u;
}

// ---------------- Kernel B: symmetric pair-block sim + exp-sum ---------
// Grid: NB*(NB+1)/2 = 2080 blocks, one per unordered pair (bi <= bj).
// Each block computes the 128x128 tile sim[bi-rows, bj-cols] once and
// contributes:  row-sums of exp -> ep[bj][rows of bi]
//               col-sums of exp -> ep[bi][cols of bj]   (bi != bj only)
// Slot coverage per row i (b = i>>7): row-side fills slots >= b, col-side
// fills slots < b -- exactly one write per ep cell, no atomics, no memset.
// Block = 4 waves x 32 rows each; 32 rows/wave keeps A-frags at 64 VGPR so
// 4 waves/SIMD fit (launch_bounds(256,4)).
__global__ __launch_bounds__(256, 4) void ntxent_main(
    const __hip_bfloat16* __restrict__ zn_,
    float* __restrict__ ep, float* __restrict__ pp) {
    const char* zn = (const char*)zn_;
    __shared__ char lds[2 * LDSBUF] __attribute__((aligned(16)));
    __shared__ float colbuf[4][BR];
    int tid = threadIdx.x, lane = tid & 63, wave = tid >> 6;
    int quad = lane >> 4, l15 = lane & 15;

    // decode linear block id -> triangular pair (bi, bj), bi <= bj
    int k = blockIdx.x;
    int bi = (int)(0.5f * (129.0f - sqrtf(16641.0f - 8.0f * (float)k)));
    if (bi < 0) bi = 0;
    if (bi > NB - 1) bi = NB - 1;
    while (bi * (129 - bi) / 2 > k) --bi;
    while ((bi + 1) * (128 - bi) / 2 <= k) ++bi;
    int bj = bi + (k - bi * (129 - bi) / 2);
    bool diagblk = (bi == bj);

    int row0 = bi * BR + wave * 32;   // this wave's 32 rows

    // A fragments: 2 tiles of 16 rows, full K=256.
    // row = row0 + s*16 + l15, k = ks*32 + quad*8 + j
    bfrag8 a[2][8];
    #pragma unroll
    for (int s = 0; s < 2; s++) {
        const char* ap = zn + (size_t)(row0 + s * 16 + l15) * 512 + quad * 16;
        #pragma unroll
        for (int ks = 0; ks < 8; ks++)
            a[s][ks] = *(const bfrag8*)(ap + ks * 64);
    }

    float es[2][4];
    #pragma unroll
    for (int s = 0; s < 2; s++)
        #pragma unroll
        for (int r = 0; r < 4; r++) es[s][r] = 0.f;

    // staging: tile = 16 cols x 512B; 256 threads x 2 x 16B
    int col0 = tid >> 5, j0 = tid & 31;
    unsigned lofs0 = col0 * LDSROW + j0 * 16;
    unsigned lofs1 = (col0 + 8) * LDSROW + j0 * 16;
    unsigned gofs0 = col0 * 512 + j0 * 16;
    unsigned gofs1 = (col0 + 8) * 512 + j0 * 16;
    const char* gbase = zn + (size_t)bj * BR * 512;

    { // preload tile 0
        uint4 r0 = *(const uint4*)(gbase + gofs0);
        uint4 r1 = *(const uint4*)(gbase + gofs1);
        *(uint4*)(lds + lofs0) = r0;
        *(uint4*)(lds + lofs1) = r1;
    }
    __syncthreads();

    for (int t = 0; t < NT; t++) {
        char* cur = lds + (t & 1) * LDSBUF;
        char* nxt = lds + ((t + 1) & 1) * LDSBUF;
        uint4 s0, s1;
        if (t + 1 < NT) {
            const char* g = gbase + (size_t)(t + 1) * CT * 512;
            s0 = *(const uint4*)(g + gofs0);
            s1 = *(const uint4*)(g + gofs1);
        }
        const char* bp = cur + l15 * LDSROW + quad * 16;

        facc4 acc[2];
        acc[0] = (facc4){0.f, 0.f, 0.f, 0.f};
        acc[1] = (facc4){0.f, 0.f, 0.f, 0.f};
        // two-pass bf[4] keeps VGPR under the 128 budget
        bfrag8 bf[4];
        #pragma unroll
        for (int ks = 0; ks < 4; ks++)
            bf[ks] = *(const bfrag8*)(bp + ks * 64);
        #pragma unroll
        for (int ks = 0; ks < 4; ks++) {
            acc[0] = __builtin_amdgcn_mfma_f32_16x16x32_bf16(a[0][ks], bf[ks], acc[0], 0, 0, 0);
            acc[1] = __builtin_amdgcn_mfma_f32_16x16x32_bf16(a[1][ks], bf[ks], acc[1], 0, 0, 0);
        }
        #pragma unroll
        for (int ks = 0; ks < 4; ks++)
            bf[ks] = *(const bfrag8*)(bp + 256 + ks * 64);
        #pragma unroll
        for (int ks = 0; ks < 4; ks++) {
            acc[0] = __builtin_amdgcn_mfma_f32_16x16x32_bf16(a[0][ks + 4], bf[ks], acc[0], 0, 0, 0);
            acc[1] = __builtin_amdgcn_mfma_f32_16x16x32_bf16(a[1][ks + 4], bf[ks], acc[1], 0, 0, 0);
        }

        int ctile = bj * BR + t * CT;
        int gcol = ctile + l15;
        float ce = 0.0f;
        bool isdiag = (ctile >> 5) == (row0 >> 5);             // only in diag blocks
        bool ispos  = (ctile >> 5) == ((row0 ^ BATCH) >> 5);   // only in (bi, bi+32)

        if (isdiag) {
            #pragma unroll
            for (int s = 0; s < 2; s++)
                #pragma unroll
                for (int r = 0; r < 4; r++) {
                    int grow = row0 + s * 16 + quad * 4 + r;
                    float e = __builtin_amdgcn_exp2f(acc[s][r] * KEXP);
                    if (gcol == grow) e = 0.0f;   // mask true diagonal
                    es[s][r] += e; ce += e;
                }
        } else {
            #pragma unroll
            for (int s = 0; s < 2; s++)
                #pragma unroll
                for (int r = 0; r < 4; r++) {
                    float e = __builtin_amdgcn_exp2f(acc[s][r] * KEXP);
                    es[s][r] += e; ce += e;
                }
            if (ispos) {
                #pragma unroll
                for (int s = 0; s < 2; s++)
                    #pragma unroll
                    for (int r = 0; r < 4; r++) {
                        int grow = row0 + s * 16 + quad * 4 + r;
                        if (gcol == (grow ^ BATCH)) {
                            float d = acc[s][r];       // raw dot; finalize scales
                            pp[grow] = d;
                            pp[grow ^ BATCH] = d;      // symmetric partner
                        }
                    }
            }
        }

        // column partial sums (transposed contribution), skip on diag blocks
        if (!diagblk) {
            ce += __shfl_xor(ce, 16);
            ce += __shfl_xor(ce, 32);
            if (lane < 16) colbuf[wave][t * CT + l15] = ce;
        }

        if (t + 1 < NT) {
            *(uint4*)(nxt + lofs0) = s0;
            *(uint4*)(nxt + lofs1) = s1;
        }
        __syncthreads();
    }

    // row-side: reduce es across the 16 column-lanes, write ep[bj][row]
    #pragma unroll
    for (int s = 0; s < 2; s++)
        #pragma unroll
        for (int r = 0; r < 4; r++) {
            float e = es[s][r];
            #pragma unroll
            for (int m = 1; m < 16; m <<= 1) e += __shfl_xor(e, m);
            if (l15 == 0)
                ep[(size_t)bj * N_ROWS + row0 + s * 16 + quad * 4 + r] = e;
        }

    // col-side: sum the 4 wave partials, write ep[bi][cols of bj]
    // (colbuf is complete: last loop iteration ended with __syncthreads)
    if (!diagblk && tid < BR) {
        float v = colbuf[0][tid] + colbuf[1][tid] + colbuf[2][tid] + colbuf[3][tid];
        ep[(size_t)bi * N_ROWS + bj * BR + tid] = v;
    }
}

// ---------------- Kernel C: combine + log + final reduce ---------------
__global__ __launch_bounds__(256) void finalize_kernel(
    const float* __restrict__ ep, const float* __restrict__ pp,
    float* __restrict__ out) {
    int tid = threadIdx.x;
    int i = blockIdx.x * 256 + tid;
    float e = 0.0f;
    #pragma unroll
    for (int s = 0; s < NB; s++) e += ep[(size_t)s * N_ROWS + i];
    float v = __logf(e) - 2.0f * pp[i];
    #pragma unroll
    for (int m = 32; m; m >>= 1) v += __shfl_xor(v, m);
    __shared__ float wsum[4];
    if ((tid & 63) == 0) wsum[tid >> 6] = v;
    __syncthreads();
    if (tid == 0)
        atomicAdd(out, (wsum[0] + wsum[1] + wsum[2] + wsum[3]) * (1.0f / N_ROWS));
}

extern "C" void kernel_launch(void* const* d_in, const int* in_sizes, int n_in,
                              void* d_out, int out_size, void* d_ws, size_t ws_size,
                              hipStream_t stream) {
    const float* zA = (const float*)d_in[0];
    const float* zB = (const float*)d_in[1];
    float* out = (float*)d_out;
    char* ws = (char*)d_ws;
    __hip_bfloat16* zn = (__hip_bfloat16*)ws;                       // 4 MB
    float* ep = (float*)(ws + (size_t)N_ROWS * DIM * 2);            // 64*8192 floats (2 MB)
    float* pp = ep + (size_t)NB * N_ROWS;                           // 8192 floats

    hipMemsetAsync(out, 0, sizeof(float), stream);
    normalize_kernel<<<N_ROWS / 4, 256, 0, stream>>>(zA, zB, zn);
    ntxent_main<<<NB * (NB + 1) / 2, 256, 0, stream>>>(zn, ep, pp);
    finalize_kernel<<<N_ROWS / 256, 256, 0, stream>>>(ep, pp, out);
}

// Round 2
// 120.235 us; speedup vs baseline: 1.0617x; 1.0617x over previous
//
#include <hip/hip_runtime.h>
#include <hip/hip_bf16.h>

#define N_ROWS 8192
#define BATCH 4096
#define DIM 256

#define NB 64           // 128-row blocks along each side
#define BR 128          // rows (and cols) per pair-block side
#define CT 16           // cols per LDS tile
#define NT 8            // tiles per block (BR/CT)
#define NBLK (NB * (NB + 1) / 2)   // 2080 pair blocks
#define LDSROW 528      // 512 data bytes + 16 pad
#define LDSBUF (CT * LDSROW)
#define KEXP 2.8853900817779268f   // 2*log2(e): exp(2*dot) = exp2(dot*KEXP)

typedef __attribute__((ext_vector_type(8))) short bfrag8;
typedef __attribute__((ext_vector_type(4))) float facc4;

// ---------------- Kernel A: normalize + cast to bf16 -------------------
__global__ __launch_bounds__(256) void normalize_kernel(
    const float* __restrict__ zA, const float* __restrict__ zB,
    __hip_bfloat16* __restrict__ zn) {
    int tid = threadIdx.x;
    int wave = tid >> 6, lane = tid & 63;
    int row = blockIdx.x * 4 + wave;
    const float* src = (row < BATCH) ? (zA + (size_t)row * DIM)
                                     : (zB + (size_t)(row - BATCH) * DIM);
    float4 v = ((const float4*)src)[lane];
    float ss = v.x * v.x + v.y * v.y + v.z * v.z + v.w * v.w;
    #pragma unroll
    for (int m = 32; m; m >>= 1) ss += __shfl_xor(ss, m);
    float inv = 1.0f / fmaxf(sqrtf(ss), 1e-8f);
    union { ushort4 u; __hip_bfloat16 h[4]; } o;
    o.h[0] = __float2bfloat16(v.x * inv);
    o.h[1] = __float2bfloat16(v.y * inv);
    o.h[2] = __float2bfloat16(v.z * inv);
    o.h[3] = __float2bfloat16(v.w * inv);
    ((ushort4*)zn)[(size_t)row * (DIM / 4) + lane] = o.u;
}

// ---------------- Kernel B: symmetric pair-block sim + exp-sum ---------
// Grid: 2080 blocks, one per unordered pair (bi <= bj). Each block computes
// the 128x128 tile sim[bi-rows, bj-cols] once and contributes:
//   row-sums of exp -> ep[bj][rows of bi]
//   col-sums of exp -> ep[bi][cols of bj]   (bi != bj only)
// Per row i (b = i>>7): row-side fills slots >= b, col-side fills slots < b
// -- exactly one write per ep cell, no atomics, no memset.
// launch_bounds(256,2): 256 unified regs/wave. a[2][8] lives in AGPRs (64),
// bf[8]+acc+es+staging in arch VGPRs (~90). (256,4) spilled 66 MB -- don't.
__global__ __launch_bounds__(256, 2) void ntxent_main(
    const __hip_bfloat16* __restrict__ zn_,
    float* __restrict__ ep, float* __restrict__ pp) {
    const char* zn = (const char*)zn_;
    __shared__ char lds[2 * LDSBUF] __attribute__((aligned(16)));
    __shared__ float colbuf[4][BR];
    int tid = threadIdx.x, lane = tid & 63, wave = tid >> 6;
    int quad = lane >> 4, l15 = lane & 15;

    // XCD-aware swizzle (bijective: 2080 % 8 == 0). Consecutive k share the
    // bi row-panel -> keep them on one XCD's L2.
    int bid = blockIdx.x;
    int k = (bid & 7) * (NBLK / 8) + (bid >> 3);

    // decode linear pair id -> (bi, bj), bi <= bj
    int bi = (int)(0.5f * (129.0f - sqrtf(16641.0f - 8.0f * (float)k)));
    if (bi < 0) bi = 0;
    if (bi > NB - 1) bi = NB - 1;
    while (bi * (129 - bi) / 2 > k) --bi;
    while ((bi + 1) * (128 - bi) / 2 <= k) ++bi;
    int bj = bi + (k - bi * (129 - bi) / 2);
    bool diagblk = (bi == bj);

    int row0 = bi * BR + wave * 32;   // this wave's 32 rows

    // A fragments: 2 tiles of 16 rows, full K=256.
    // row = row0 + s*16 + l15, k = ks*32 + quad*8 + j
    bfrag8 a[2][8];
    #pragma unroll
    for (int s = 0; s < 2; s++) {
        const char* ap = zn + (size_t)(row0 + s * 16 + l15) * 512 + quad * 16;
        #pragma unroll
        for (int ks = 0; ks < 8; ks++)
            a[s][ks] = *(const bfrag8*)(ap + ks * 64);
    }

    float es[2][4];
    #pragma unroll
    for (int s = 0; s < 2; s++)
        #pragma unroll
        for (int r = 0; r < 4; r++) es[s][r] = 0.f;

    // staging: tile = 16 cols x 512B; 256 threads x 2 x 16B
    int col0 = tid >> 5, j0 = tid & 31;
    unsigned lofs0 = col0 * LDSROW + j0 * 16;
    unsigned lofs1 = (col0 + 8) * LDSROW + j0 * 16;
    unsigned gofs0 = col0 * 512 + j0 * 16;
    unsigned gofs1 = (col0 + 8) * 512 + j0 * 16;
    const char* gbase = zn + (size_t)bj * BR * 512;

    { // preload tile 0
        uint4 r0 = *(const uint4*)(gbase + gofs0);
        uint4 r1 = *(const uint4*)(gbase + gofs1);
        *(uint4*)(lds + lofs0) = r0;
        *(uint4*)(lds + lofs1) = r1;
    }
    __syncthreads();

    for (int t = 0; t < NT; t++) {
        char* cur = lds + (t & 1) * LDSBUF;
        char* nxt = lds + ((t + 1) & 1) * LDSBUF;
        uint4 s0, s1;
        if (t + 1 < NT) {
            const char* g = gbase + (size_t)(t + 1) * CT * 512;
            s0 = *(const uint4*)(g + gofs0);
            s1 = *(const uint4*)(g + gofs1);
        }
        const char* bp = cur + l15 * LDSROW + quad * 16;
        bfrag8 bf[8];
        #pragma unroll
        for (int ks = 0; ks < 8; ks++)
            bf[ks] = *(const bfrag8*)(bp + ks * 64);

        facc4 acc[2];
        acc[0] = (facc4){0.f, 0.f, 0.f, 0.f};
        acc[1] = (facc4){0.f, 0.f, 0.f, 0.f};
        #pragma unroll
        for (int ks = 0; ks < 8; ks++) {
            acc[0] = __builtin_amdgcn_mfma_f32_16x16x32_bf16(a[0][ks], bf[ks], acc[0], 0, 0, 0);
            acc[1] = __builtin_amdgcn_mfma_f32_16x16x32_bf16(a[1][ks], bf[ks], acc[1], 0, 0, 0);
        }

        int ctile = bj * BR + t * CT;
        int gcol = ctile + l15;
        float ce = 0.0f;
        bool isdiag = (ctile >> 5) == (row0 >> 5);             // only in diag blocks
        bool ispos  = (ctile >> 5) == ((row0 ^ BATCH) >> 5);   // only in (bi, bi+32)

        if (isdiag) {
            #pragma unroll
            for (int s = 0; s < 2; s++)
                #pragma unroll
                for (int r = 0; r < 4; r++) {
                    int grow = row0 + s * 16 + quad * 4 + r;
                    float e = __builtin_amdgcn_exp2f(acc[s][r] * KEXP);
                    if (gcol == grow) e = 0.0f;   // mask true diagonal
                    es[s][r] += e; ce += e;
                }
        } else {
            #pragma unroll
            for (int s = 0; s < 2; s++)
                #pragma unroll
                for (int r = 0; r < 4; r++) {
                    float e = __builtin_amdgcn_exp2f(acc[s][r] * KEXP);
                    es[s][r] += e; ce += e;
                }
            if (ispos) {
                #pragma unroll
                for (int s = 0; s < 2; s++)
                    #pragma unroll
                    for (int r = 0; r < 4; r++) {
                        int grow = row0 + s * 16 + quad * 4 + r;
                        if (gcol == (grow ^ BATCH)) {
                            float d = acc[s][r];       // raw dot; finalize scales
                            pp[grow] = d;
                            pp[grow ^ BATCH] = d;      // symmetric partner
                        }
                    }
            }
        }

        // column partial sums (transposed contribution), skip on diag blocks
        if (!diagblk) {
            ce += __shfl_xor(ce, 16);
            ce += __shfl_xor(ce, 32);
            if (lane < 16) colbuf[wave][t * CT + l15] = ce;
        }

        if (t + 1 < NT) {
            *(uint4*)(nxt + lofs0) = s0;
            *(uint4*)(nxt + lofs1) = s1;
        }
        __syncthreads();
    }

    // row-side: reduce es across the 16 column-lanes, write ep[bj][row]
    #pragma unroll
    for (int s = 0; s < 2; s++)
        #pragma unroll
        for (int r = 0; r < 4; r++) {
            float e = es[s][r];
            #pragma unroll
            for (int m = 1; m < 16; m <<= 1) e += __shfl_xor(e, m);
            if (l15 == 0)
                ep[(size_t)bj * N_ROWS + row0 + s * 16 + quad * 4 + r] = e;
        }

    // col-side: sum the 4 wave partials, write ep[bi][cols of bj]
    // (colbuf is complete: last loop iteration ended with __syncthreads)
    if (!diagblk && tid < BR) {
        float v = colbuf[0][tid] + colbuf[1][tid] + colbuf[2][tid] + colbuf[3][tid];
        ep[(size_t)bi * N_ROWS + bj * BR + tid] = v;
    }
}

// ---------------- Kernel C: combine + log + final reduce ---------------
__global__ __launch_bounds__(256) void finalize_kernel(
    const float* __restrict__ ep, const float* __restrict__ pp,
    float* __restrict__ out) {
    int tid = threadIdx.x;
    int i = blockIdx.x * 256 + tid;
    float e = 0.0f;
    #pragma unroll
    for (int s = 0; s < NB; s++) e += ep[(size_t)s * N_ROWS + i];
    float v = __logf(e) - 2.0f * pp[i];
    #pragma unroll
    for (int m = 32; m; m >>= 1) v += __shfl_xor(v, m);
    __shared__ float wsum[4];
    if ((tid & 63) == 0) wsum[tid >> 6] = v;
    __syncthreads();
    if (tid == 0)
        atomicAdd(out, (wsum[0] + wsum[1] + wsum[2] + wsum[3]) * (1.0f / N_ROWS));
}

extern "C" void kernel_launch(void* const* d_in, const int* in_sizes, int n_in,
                              void* d_out, int out_size, void* d_ws, size_t ws_size,
                              hipStream_t stream) {
    const float* zA = (const float*)d_in[0];
    const float* zB = (const float*)d_in[1];
    float* out = (float*)d_out;
    char* ws = (char*)d_ws;
    __hip_bfloat16* zn = (__hip_bfloat16*)ws;                       // 4 MB
    float* ep = (float*)(ws + (size_t)N_ROWS * DIM * 2);            // 64*8192 floats (2 MB)
    float* pp = ep + (size_t)NB * N_ROWS;                           // 8192 floats

    hipMemsetAsync(out, 0, sizeof(float), stream);
    normalize_kernel<<<N_ROWS / 4, 256, 0, stream>>>(zA, zB, zn);
    ntxent_main<<<NBLK, 256, 0, stream>>>(zn, ep, pp);
    finalize_kernel<<<N_ROWS / 256, 256, 0, stream>>>(ep, pp, out);
}

// Round 3
// 119.439 us; speedup vs baseline: 1.0688x; 1.0067x over previous
//
#include <hip/hip_runtime.h>
#include <hip/hip_bf16.h>

#define N_ROWS 8192
#define BATCH 4096
#define DIM 256

#define NB 64           // 128-row blocks along each side
#define BR 128          // rows (and cols) per pair-block side
#define CT 16           // cols per LDS tile
#define NT 8            // tiles per block (BR/CT)
#define NBLK (NB * (NB + 1) / 2)   // 2080 pair blocks
#define LDSROW 528      // 512 data bytes + 16 pad
#define LDSBUF (CT * LDSROW)
#define KEXP 2.8853900817779268f   // 2*log2(e): exp(2*dot) = exp2(dot*KEXP)

typedef __attribute__((ext_vector_type(8))) short bfrag8;
typedef __attribute__((ext_vector_type(4))) float facc4;

// ---------------- Kernel A: normalize + cast to bf16 -------------------
__global__ __launch_bounds__(256) void normalize_kernel(
    const float* __restrict__ zA, const float* __restrict__ zB,
    __hip_bfloat16* __restrict__ zn) {
    int tid = threadIdx.x;
    int wave = tid >> 6, lane = tid & 63;
    int row = blockIdx.x * 4 + wave;
    const float* src = (row < BATCH) ? (zA + (size_t)row * DIM)
                                     : (zB + (size_t)(row - BATCH) * DIM);
    float4 v = ((const float4*)src)[lane];
    float ss = v.x * v.x + v.y * v.y + v.z * v.z + v.w * v.w;
    #pragma unroll
    for (int m = 32; m; m >>= 1) ss += __shfl_xor(ss, m);
    float inv = 1.0f / fmaxf(sqrtf(ss), 1e-8f);
    union { ushort4 u; __hip_bfloat16 h[4]; } o;
    o.h[0] = __float2bfloat16(v.x * inv);
    o.h[1] = __float2bfloat16(v.y * inv);
    o.h[2] = __float2bfloat16(v.z * inv);
    o.h[3] = __float2bfloat16(v.w * inv);
    ((ushort4*)zn)[(size_t)row * (DIM / 4) + lane] = o.u;
}

// ---------------- Kernel B: symmetric pair-block sim + exp-sum ---------
// Grid: 2080 blocks, one per unordered pair (bi <= bj). Each block computes
// the 128x128 tile sim[bi-rows, bj-cols] once and contributes:
//   row-sums of exp -> ep[bj][rows of bi]
//   col-sums of exp -> ep[bi][cols of bj]   (bi != bj only)
// Per row i (b = i>>7): row-side fills slots >= b, col-side fills slots < b
// -- exactly one write per ep cell, no atomics, no memset.
//
// Register budget history (counters): (256,4)=128-cap -> 66 MB spill. At
// (256,2) measured allocation = 80 arch VGPR + 64 AGPR = 144. (256,3) caps
// at 170 >= 144+slack -> 3 waves/SIMD, no spill expected. Latency-bound
// kernel (all pipes <25%): occupancy is the direct lever.
__global__ __launch_bounds__(256, 3) void ntxent_main(
    const __hip_bfloat16* __restrict__ zn_,
    float* __restrict__ ep, float* __restrict__ pp) {
    const char* zn = (const char*)zn_;
    __shared__ char lds[2 * LDSBUF] __attribute__((aligned(16)));
    __shared__ float colbuf[4][BR];
    int tid = threadIdx.x, lane = tid & 63, wave = tid >> 6;
    int quad = lane >> 4, l15 = lane & 15;

    // XCD-aware swizzle (bijective: 2080 % 8 == 0). Consecutive k share the
    // bi row-panel -> keep them on one XCD's L2.
    int bid = blockIdx.x;
    int k = (bid & 7) * (NBLK / 8) + (bid >> 3);

    // decode linear pair id -> (bi, bj), bi <= bj
    int bi = (int)(0.5f * (129.0f - sqrtf(16641.0f - 8.0f * (float)k)));
    if (bi < 0) bi = 0;
    if (bi > NB - 1) bi = NB - 1;
    while (bi * (129 - bi) / 2 > k) --bi;
    while ((bi + 1) * (128 - bi) / 2 <= k) ++bi;
    int bj = bi + (k - bi * (129 - bi) / 2);
    bool diagblk = (bi == bj);

    int row0 = bi * BR + wave * 32;   // this wave's 32 rows

    // staging geometry: tile = 16 cols x 512B; 256 threads x 2 x 16B
    int col0 = tid >> 5, j0 = tid & 31;
    unsigned lofs0 = col0 * LDSROW + j0 * 16;
    unsigned lofs1 = (col0 + 8) * LDSROW + j0 * 16;
    unsigned gofs0 = col0 * 512 + j0 * 16;
    unsigned gofs1 = (col0 + 8) * 512 + j0 * 16;
    const char* gbase = zn + (size_t)bj * BR * 512;

    // issue tile-0 staging loads FIRST (needed by the first barrier; the
    // A-frag loads below are needed slightly later and overlap this)
    uint4 p0 = *(const uint4*)(gbase + gofs0);
    uint4 p1 = *(const uint4*)(gbase + gofs1);

    // A fragments: 2 tiles of 16 rows, full K=256.
    // row = row0 + s*16 + l15, k = ks*32 + quad*8 + j
    bfrag8 a[2][8];
    #pragma unroll
    for (int s = 0; s < 2; s++) {
        const char* ap = zn + (size_t)(row0 + s * 16 + l15) * 512 + quad * 16;
        #pragma unroll
        for (int ks = 0; ks < 8; ks++)
            a[s][ks] = *(const bfrag8*)(ap + ks * 64);
    }

    float es[2][4];
    #pragma unroll
    for (int s = 0; s < 2; s++)
        #pragma unroll
        for (int r = 0; r < 4; r++) es[s][r] = 0.f;

    *(uint4*)(lds + lofs0) = p0;
    *(uint4*)(lds + lofs1) = p1;
    __syncthreads();

    for (int t = 0; t < NT; t++) {
        char* cur = lds + (t & 1) * LDSBUF;
        char* nxt = lds + ((t + 1) & 1) * LDSBUF;
        uint4 s0, s1;
        if (t + 1 < NT) {
            const char* g = gbase + (size_t)(t + 1) * CT * 512;
            s0 = *(const uint4*)(g + gofs0);
            s1 = *(const uint4*)(g + gofs1);
        }
        const char* bp = cur + l15 * LDSROW + quad * 16;
        bfrag8 bf[8];
        #pragma unroll
        for (int ks = 0; ks < 8; ks++)
            bf[ks] = *(const bfrag8*)(bp + ks * 64);

        facc4 acc[2];
        acc[0] = (facc4){0.f, 0.f, 0.f, 0.f};
        acc[1] = (facc4){0.f, 0.f, 0.f, 0.f};
        #pragma unroll
        for (int ks = 0; ks < 8; ks++) {
            acc[0] = __builtin_amdgcn_mfma_f32_16x16x32_bf16(a[0][ks], bf[ks], acc[0], 0, 0, 0);
            acc[1] = __builtin_amdgcn_mfma_f32_16x16x32_bf16(a[1][ks], bf[ks], acc[1], 0, 0, 0);
        }

        int ctile = bj * BR + t * CT;
        int gcol = ctile + l15;
        float ce = 0.0f;
        bool isdiag = (ctile >> 5) == (row0 >> 5);             // only in diag blocks
        bool ispos  = (ctile >> 5) == ((row0 ^ BATCH) >> 5);   // only in (bi, bi+32)

        if (isdiag) {
            #pragma unroll
            for (int s = 0; s < 2; s++)
                #pragma unroll
                for (int r = 0; r < 4; r++) {
                    int grow = row0 + s * 16 + quad * 4 + r;
                    float e = __builtin_amdgcn_exp2f(acc[s][r] * KEXP);
                    if (gcol == grow) e = 0.0f;   // mask true diagonal
                    es[s][r] += e; ce += e;
                }
        } else {
            #pragma unroll
            for (int s = 0; s < 2; s++)
                #pragma unroll
                for (int r = 0; r < 4; r++) {
                    float e = __builtin_amdgcn_exp2f(acc[s][r] * KEXP);
                    es[s][r] += e; ce += e;
                }
            if (ispos) {
                #pragma unroll
                for (int s = 0; s < 2; s++)
                    #pragma unroll
                    for (int r = 0; r < 4; r++) {
                        int grow = row0 + s * 16 + quad * 4 + r;
                        if (gcol == (grow ^ BATCH)) {
                            float d = acc[s][r];       // raw dot; finalize scales
                            pp[grow] = d;
                            pp[grow ^ BATCH] = d;      // symmetric partner
                        }
                    }
            }
        }

        // column partial sums (transposed contribution), skip on diag blocks
        if (!diagblk) {
            ce += __shfl_xor(ce, 16);
            ce += __shfl_xor(ce, 32);
            if (lane < 16) colbuf[wave][t * CT + l15] = ce;
        }

        if (t + 1 < NT) {
            *(uint4*)(nxt + lofs0) = s0;
            *(uint4*)(nxt + lofs1) = s1;
        }
        __syncthreads();
    }

    // row-side: reduce es across the 16 column-lanes, write ep[bj][row]
    #pragma unroll
    for (int s = 0; s < 2; s++)
        #pragma unroll
        for (int r = 0; r < 4; r++) {
            float e = es[s][r];
            #pragma unroll
            for (int m = 1; m < 16; m <<= 1) e += __shfl_xor(e, m);
            if (l15 == 0)
                ep[(size_t)bj * N_ROWS + row0 + s * 16 + quad * 4 + r] = e;
        }

    // col-side: sum the 4 wave partials, write ep[bi][cols of bj]
    // (colbuf is complete: last loop iteration ended with __syncthreads)
    if (!diagblk && tid < BR) {
        float v = colbuf[0][tid] + colbuf[1][tid] + colbuf[2][tid] + colbuf[3][tid];
        ep[(size_t)bi * N_ROWS + bj * BR + tid] = v;
    }
}

// ---------------- Kernel C: combine + log + final reduce ---------------
__global__ __launch_bounds__(256) void finalize_kernel(
    const float* __restrict__ ep, const float* __restrict__ pp,
    float* __restrict__ out) {
    int tid = threadIdx.x;
    int i = blockIdx.x * 256 + tid;
    float e = 0.0f;
    #pragma unroll
    for (int s = 0; s < NB; s++) e += ep[(size_t)s * N_ROWS + i];
    float v = __logf(e) - 2.0f * pp[i];
    #pragma unroll
    for (int m = 32; m; m >>= 1) v += __shfl_xor(v, m);
    __shared__ float wsum[4];
    if ((tid & 63) == 0) wsum[tid >> 6] = v;
    __syncthreads();
    if (tid == 0)
        atomicAdd(out, (wsum[0] + wsum[1] + wsum[2] + wsum[3]) * (1.0f / N_ROWS));
}

extern "C" void kernel_launch(void* const* d_in, const int* in_sizes, int n_in,
                              void* d_out, int out_size, void* d_ws, size_t ws_size,
                              hipStream_t stream) {
    const float* zA = (const float*)d_in[0];
    const float* zB = (const float*)d_in[1];
    float* out = (float*)d_out;
    char* ws = (char*)d_ws;
    __hip_bfloat16* zn = (__hip_bfloat16*)ws;                       // 4 MB
    float* ep = (float*)(ws + (size_t)N_ROWS * DIM * 2);            // 64*8192 floats (2 MB)
    float* pp = ep + (size_t)NB * N_ROWS;                           // 8192 floats

    hipMemsetAsync(out, 0, sizeof(float), stream);
    normalize_kernel<<<N_ROWS / 4, 256, 0, stream>>>(zA, zB, zn);
    ntxent_main<<<NBLK, 256, 0, stream>>>(zn, ep, pp);
    finalize_kernel<<<N_ROWS / 256, 256, 0, stream>>>(ep, pp, out);
}